// Round 3
// baseline (374.808 us; speedup 1.0000x reference)
//
#include <hip/hip_runtime.h>
#include <math.h>

typedef __bf16 bf16;
typedef __bf16 bf16x8 __attribute__((ext_vector_type(8)));
typedef float f32x4 __attribute__((ext_vector_type(4)));

#define MFMA16(a,b,c) __builtin_amdgcn_mfma_f32_16x16x32_bf16((a),(b),(c),0,0,0)

#define D 256
#define H 4
#define A 32
#define P 4
#define HA 128
#define RHID 64
#define ROWS 64
#define NROWS_TOT 262144
#define SCALE_F 0.17677669529663687f

// ws offsets in bf16 elements
#define OFF_Q  0
#define OFF_F  32768
#define OFF_G1 65536
#define OFF_G2 81920
#define OFF_O  98304
#define NPACK  102400

__device__ __forceinline__ float fast_exp(float x) { return __expf(x); }
__device__ __forceinline__ float fast_rcp(float x) { return __builtin_amdgcn_rcpf(x); }

// ---------------- weight prepack: f32 -> bf16 in MFMA B-fragment order ----------------
// B-fragment for 16x16x32: lane l holds col n = l&15, k = (l>>4)*8 + j (j=0..7, contiguous)
__global__ __launch_bounds__(256)
void prep_kernel(const float* __restrict__ Wq, const float* __restrict__ Wf,
                 const float* __restrict__ Wg1, const float* __restrict__ Wg2,
                 const float* __restrict__ Wo, bf16* __restrict__ ws)
{
  int i = blockIdx.x * 256 + threadIdx.x;
  if (i >= NPACK) return;
  float v;
  if (i < OFF_F) {              // packQ [h(4)][ks(8)][nt(2)][l(64)][j(8)], K=256,N=32 per head
    int j = i & 7, l = (i >> 3) & 63, nt = (i >> 9) & 1, ks = (i >> 10) & 7, h = i >> 13;
    int k = ks * 32 + (l >> 4) * 8 + j, n = nt * 16 + (l & 15);
    v = Wq[(h * 256 + k) * 32 + n];
  } else if (i < OFF_G1) {      // packF [ks(4)][gnt(16)][l][j], K=128,N=256
    int ii = i - OFF_F;
    int j = ii & 7, l = (ii >> 3) & 63, g = (ii >> 9) & 15, ks = ii >> 13;
    int k = ks * 32 + (l >> 4) * 8 + j, n = g * 16 + (l & 15);
    v = Wf[k * 256 + n];
  } else if (i < OFF_G2) {      // packG1 [ks(8)][nt(4)][l][j], K=256,N=64 (row 256 added via s_wg1d)
    int ii = i - OFF_G1;
    int j = ii & 7, l = (ii >> 3) & 63, nt = (ii >> 9) & 3, ks = ii >> 11;
    int k = ks * 32 + (l >> 4) * 8 + j, n = nt * 16 + (l & 15);
    v = Wg1[k * 64 + n];
  } else if (i < OFF_O) {       // packG2 [ks(2)][gnt(16)][l][j], K=64,N=256
    int ii = i - OFF_G2;
    int j = ii & 7, l = (ii >> 3) & 63, g = (ii >> 9) & 15, ks = ii >> 13;
    int k = ks * 32 + (l >> 4) * 8 + j, n = g * 16 + (l & 15);
    v = Wg2[k * 256 + n];
  } else {                      // packO [h(4)][nt(2)][l][j], K=32,N=32 per head
    int ii = i - OFF_O;
    int j = ii & 7, l = (ii >> 3) & 63, nt = (ii >> 9) & 1, h = ii >> 10;
    int k = (l >> 4) * 8 + j, n = nt * 16 + (l & 15);
    v = Wo[(h * 32 + k) * 32 + n];
  }
  ws[i] = (bf16)v;
}

// ---------------- fused main kernel: 64 rows/block, 4 waves, 5 MFMA GEMMs ----------------
// LDS budget ~52 KB -> 3 blocks/CU.
__global__ __launch_bounds__(256, 3)
void faiia_kernel(const float* __restrict__ x, const float* __restrict__ mp,
    const float* __restrict__ bq, const float* __restrict__ pk,
    const float* __restrict__ pv, const float* __restrict__ imp,
    const float* __restrict__ fa, const float* __restrict__ ft,
    const float* __restrict__ bo, const float* __restrict__ lng,
    const float* __restrict__ lnb, const float* __restrict__ bfb,
    const float* __restrict__ Wg1, const float* __restrict__ bg1,
    const float* __restrict__ bg2, const float* __restrict__ lnFg,
    const float* __restrict__ lnFb, const bf16* __restrict__ ws,
    float* __restrict__ out)
{
  // region A (32KB), multi-use:
  //   [stage]   xfrag   [mt4][ks8][64][8]                (full 32KB)
  //   [GEMM1->B] s_q    upper 16KB: row-major 64x128 bf16, XOR-swizzled
  //   [B->Wo]   attfrag [h4][mt4][64][8]                 (lower 16KB)
  //   [Wo->G2]  combfrag [ks2:4][mt4][64][8]             (upper 16KB)
  //   [G2->G3]  opfrag  [ks3:8][mt4][64][8]              (full 32KB)
  __shared__ __attribute__((aligned(16))) bf16 s_regA[16384];
  __shared__ __attribute__((aligned(16))) bf16 s_hfrag[4096];   // hidden frag; later LN scratch (f32)
  __shared__ float s_pk[H*P*A], s_pv[H*P*A], s_imp[H*P], s_fa[H], s_ft[H];
  __shared__ float s_bq[HA], s_bo[HA], s_lng[HA], s_lnb[HA];
  __shared__ float s_bf[D], s_bg1[RHID], s_wg1d[RHID], s_bg2[D], s_lnFg[D], s_lnFb[D];
  __shared__ float s_diff[ROWS];

  bf16* s_q = s_regA + 8192;                 // aliases upper 16KB of region A
  float* s_lnsum = reinterpret_cast<float*>(s_hfrag);        // 256 f32
  float* s_lnsq  = s_lnsum + 256;                            // 256 f32
  float* s_rmean = s_lnsq + 256;                             // 64 f32
  float* s_rrstd = s_rmean + 64;                             // 64 f32

  const int t = threadIdx.x;
  const int lane = t & 63;
  const int w = t >> 6;           // wave id
  const int lr = lane >> 4;       // row-group 0..3
  const int lc = lane & 15;       // col-in-tile
  const int row0 = blockIdx.x * ROWS;

  // ---- stage small constants ----
  for (int i = t; i < H*P*A; i += 256) { s_pk[i] = pk[i]; s_pv[i] = pv[i]; }
  if (t < H*P) s_imp[t] = imp[t];
  if (t < H) { s_fa[t] = fa[t]; s_ft[t] = ft[t]; }
  if (t < HA) { s_bq[t] = bq[t]; s_bo[t] = bo[t]; s_lng[t] = lng[t]; s_lnb[t] = lnb[t]; }
  s_bf[t] = bfb[t]; s_bg2[t] = bg2[t]; s_lnFg[t] = lnFg[t]; s_lnFb[t] = lnFb[t];
  if (t < RHID) { s_bg1[t] = bg1[t]; s_wg1d[t] = Wg1[256*RHID + t]; }
  if (t < ROWS) { float m = mp[row0 + t]; s_diff[t] = 1.f - 2.f*fabsf(m - 0.5f); }

  // ---- stage x -> bf16 A-fragments: slot s = (mt*8+ks)*64 + l ----
  {
    const float* xbase = x + (size_t)row0 * D;
    #pragma unroll
    for (int i = 0; i < 8; ++i) {
      int s = t + 256*i;
      int l = s & 63, ks = (s >> 6) & 7, mt = s >> 9;
      int row = mt*16 + (l & 15);
      int k0 = ks*32 + ((l >> 4) & 3)*8;
      const float* xp = xbase + row*D + k0;
      float4 v0 = *reinterpret_cast<const float4*>(xp);
      float4 v1 = *reinterpret_cast<const float4*>(xp + 4);
      bf16x8 fr;
      fr[0]=(bf16)v0.x; fr[1]=(bf16)v0.y; fr[2]=(bf16)v0.z; fr[3]=(bf16)v0.w;
      fr[4]=(bf16)v1.x; fr[5]=(bf16)v1.y; fr[6]=(bf16)v1.z; fr[7]=(bf16)v1.w;
      *reinterpret_cast<bf16x8*>(&s_regA[(size_t)s * 8]) = fr;
    }
  }
  __syncthreads();

  // ---- GEMM1: Q = X(64x256) * Wq[head=w](256x32); wave w computes head w ----
  {
    f32x4 acc[4][2];
    #pragma unroll
    for (int mt = 0; mt < 4; ++mt) { acc[mt][0] = (f32x4)0.f; acc[mt][1] = (f32x4)0.f; }
    const bf16x8* pQ = reinterpret_cast<const bf16x8*>(ws + OFF_Q);
    #pragma unroll
    for (int ks = 0; ks < 8; ++ks) {
      bf16x8 b0 = pQ[((w*8 + ks)*2 + 0)*64 + lane];
      bf16x8 b1 = pQ[((w*8 + ks)*2 + 1)*64 + lane];
      #pragma unroll
      for (int mt = 0; mt < 4; ++mt) {
        bf16x8 a = *reinterpret_cast<const bf16x8*>(&s_regA[((mt*8 + ks)*64 + lane)*8]);
        acc[mt][0] = MFMA16(a, b0, acc[mt][0]);
        acc[mt][1] = MFMA16(a, b1, acc[mt][1]);
      }
    }
    __syncthreads();   // all xfrag reads done before s_q overwrites upper 16KB
    float bq0 = s_bq[w*32 + lc], bq1 = s_bq[w*32 + 16 + lc];
    #pragma unroll
    for (int mt = 0; mt < 4; ++mt)
      #pragma unroll
      for (int r = 0; r < 4; ++r) {
        int row = mt*16 + lr*4 + r;
        int sw = (row & 7) << 3;                 // XOR swizzle (in bf16 elements)
        int c0 = (w*32 + lc) ^ sw;
        int c1 = (w*32 + 16 + lc) ^ sw;
        s_q[row*128 + c0] = (bf16)(acc[mt][0][r] + bq0);
        s_q[row*128 + c1] = (bf16)(acc[mt][1][r] + bq1);
      }
  }
  __syncthreads();

  // ---- Phase B: prototype attention, thread = (row, head); writes attfrag (lower 16KB) ----
  {
    const int r = t >> 2, h = t & 3;
    const int swr = (r & 7) << 3;
    float q[32];
    #pragma unroll
    for (int g = 0; g < 4; ++g) {
      int c0 = (h*32 + g*8) ^ swr;               // 8-aligned: swizzle only flips bits >=3
      bf16x8 v = *reinterpret_cast<const bf16x8*>(&s_q[r*128 + c0]);
      #pragma unroll
      for (int j = 0; j < 8; ++j) q[g*8 + j] = (float)v[j];
    }
    float u = s_diff[r];
    float up = u + 1e-8f;
    float mod = 1.f + s_fa[h]*up*up*s_ft[h];
    float sc[4];
    #pragma unroll
    for (int p = 0; p < 4; ++p) {
      float s = s_imp[h*4 + p];
      const float4* kp = reinterpret_cast<const float4*>(&s_pk[(h*4 + p)*32]);
      #pragma unroll
      for (int g = 0; g < 8; ++g) {
        float4 kv = kp[g];
        s = fmaf(q[g*4+0], kv.x, s); s = fmaf(q[g*4+1], kv.y, s);
        s = fmaf(q[g*4+2], kv.z, s); s = fmaf(q[g*4+3], kv.w, s);
      }
      sc[p] = s * mod * SCALE_F;
    }
    float mx = fmaxf(fmaxf(sc[0], sc[1]), fmaxf(sc[2], sc[3]));
    float e0 = fast_exp(sc[0]-mx), e1 = fast_exp(sc[1]-mx);
    float e2 = fast_exp(sc[2]-mx), e3 = fast_exp(sc[3]-mx);
    float inv = fast_rcp(e0+e1+e2+e3);
    e0 *= inv; e1 *= inv; e2 *= inv; e3 *= inv;
    const float4* p0 = reinterpret_cast<const float4*>(&s_pv[(h*4+0)*32]);
    const float4* p1 = reinterpret_cast<const float4*>(&s_pv[(h*4+1)*32]);
    const float4* p2 = reinterpret_cast<const float4*>(&s_pv[(h*4+2)*32]);
    const float4* p3 = reinterpret_cast<const float4*>(&s_pv[(h*4+3)*32]);
    const int mt = r >> 4, rl = r & 15;
    #pragma unroll
    for (int g = 0; g < 4; ++g) {
      float4 a0 = p0[g*2],   b0v = p0[g*2+1];
      float4 a1 = p1[g*2],   b1v = p1[g*2+1];
      float4 a2 = p2[g*2],   b2v = p2[g*2+1];
      float4 a3 = p3[g*2],   b3v = p3[g*2+1];
      bf16x8 av;
      av[0] = (bf16)(e0*a0.x + e1*a1.x + e2*a2.x + e3*a3.x);
      av[1] = (bf16)(e0*a0.y + e1*a1.y + e2*a2.y + e3*a3.y);
      av[2] = (bf16)(e0*a0.z + e1*a1.z + e2*a2.z + e3*a3.z);
      av[3] = (bf16)(e0*a0.w + e1*a1.w + e2*a2.w + e3*a3.w);
      av[4] = (bf16)(e0*b0v.x + e1*b1v.x + e2*b2v.x + e3*b3v.x);
      av[5] = (bf16)(e0*b0v.y + e1*b1v.y + e2*b2v.y + e3*b3v.y);
      av[6] = (bf16)(e0*b0v.z + e1*b1v.z + e2*b2v.z + e3*b3v.z);
      av[7] = (bf16)(e0*b0v.w + e1*b1v.w + e2*b2v.w + e3*b3v.w);
      *reinterpret_cast<bf16x8*>(&s_regA[(((h*4) + mt)*64 + g*16 + rl)*8]) = av;
    }
  }
  __syncthreads();

  // ---- Wo-GEMM + per-head LN; wave w = head w; writes combfrag (upper 16KB, over dead s_q) ----
  {
    f32x4 acc[4][2];
    #pragma unroll
    for (int mt = 0; mt < 4; ++mt) { acc[mt][0] = (f32x4)0.f; acc[mt][1] = (f32x4)0.f; }
    const bf16x8* pO = reinterpret_cast<const bf16x8*>(ws + OFF_O);
    bf16x8 b0 = pO[(w*2 + 0)*64 + lane];
    bf16x8 b1 = pO[(w*2 + 1)*64 + lane];
    #pragma unroll
    for (int mt = 0; mt < 4; ++mt) {
      bf16x8 a = *reinterpret_cast<const bf16x8*>(&s_regA[((w*4 + mt)*64 + lane)*8]);
      acc[mt][0] = MFMA16(a, b0, acc[mt][0]);
      acc[mt][1] = MFMA16(a, b1, acc[mt][1]);
    }
    float bo0 = s_bo[w*32 + lc],  bo1 = s_bo[w*32 + 16 + lc];
    float lg0 = s_lng[w*32 + lc], lg1 = s_lng[w*32 + 16 + lc];
    float lb0 = s_lnb[w*32 + lc], lb1 = s_lnb[w*32 + 16 + lc];
    #pragma unroll
    for (int mt = 0; mt < 4; ++mt)
      #pragma unroll
      for (int r = 0; r < 4; ++r) {
        float v0 = acc[mt][0][r] + bo0;
        float v1 = acc[mt][1][r] + bo1;
        float s = v0 + v1, sq = v0*v0 + v1*v1;
        s += __shfl_xor(s, 1, 64);  sq += __shfl_xor(sq, 1, 64);
        s += __shfl_xor(s, 2, 64);  sq += __shfl_xor(sq, 2, 64);
        s += __shfl_xor(s, 4, 64);  sq += __shfl_xor(sq, 4, 64);
        s += __shfl_xor(s, 8, 64);  sq += __shfl_xor(sq, 8, 64);
        float mean = s * (1.f/32.f);
        float var  = sq * (1.f/32.f) - mean*mean;
        float rstd = rsqrtf(var + 1e-5f);
        float n0 = (v0 - mean)*rstd*lg0 + lb0;
        float n1 = (v1 - mean)*rstd*lg1 + lb1;
        int rl = lr*4 + r;
        int base = 8192 + ((w*4 + mt)*64)*8;
        s_regA[base + (16*(lc >> 3)       + rl)*8 + (lane & 7)] = (bf16)n0;
        s_regA[base + (16*(2 + (lc >> 3)) + rl)*8 + (lane & 7)] = (bf16)n1;
      }
  }
  __syncthreads();

  // ---- GEMM2: out_pre = combined(64x128) * Wf(128x256); wave w -> cols [64w,64w+64) ----
  f32x4 acc2[4][4];
  {
    #pragma unroll
    for (int mt = 0; mt < 4; ++mt)
      #pragma unroll
      for (int nt = 0; nt < 4; ++nt) acc2[mt][nt] = (f32x4)0.f;
    const bf16x8* pF = reinterpret_cast<const bf16x8*>(ws + OFF_F);
    #pragma unroll
    for (int ks = 0; ks < 4; ++ks) {
      bf16x8 a[4], bb[4];
      #pragma unroll
      for (int mt = 0; mt < 4; ++mt)
        a[mt] = *reinterpret_cast<const bf16x8*>(&s_regA[8192 + ((ks*4 + mt)*64 + lane)*8]);
      #pragma unroll
      for (int nt = 0; nt < 4; ++nt)
        bb[nt] = pF[(ks*16 + w*4 + nt)*64 + lane];
      #pragma unroll
      for (int mt = 0; mt < 4; ++mt)
        #pragma unroll
        for (int nt = 0; nt < 4; ++nt)
          acc2[mt][nt] = MFMA16(a[mt], bb[nt], acc2[mt][nt]);
    }
    #pragma unroll
    for (int nt = 0; nt < 4; ++nt) {
      float bfv = s_bf[w*64 + nt*16 + lc];
      #pragma unroll
      for (int mt = 0; mt < 4; ++mt)
        #pragma unroll
        for (int r = 0; r < 4; ++r) acc2[mt][nt][r] += bfv;
    }
  }
  __syncthreads();   // all combfrag reads done before opfrag overwrites region A
  {
    #pragma unroll
    for (int mt = 0; mt < 4; ++mt)
      #pragma unroll
      for (int nt = 0; nt < 4; ++nt) {
        int ks3 = w*2 + (nt >> 1);
        #pragma unroll
        for (int r = 0; r < 4; ++r) {
          int lane2 = 16*((nt & 1)*2 + (lc >> 3)) + (lr*4 + r);
          s_regA[((ks3*4 + mt)*64 + lane2)*8 + (lane & 7)] = (bf16)acc2[mt][nt][r];
        }
      }
  }
  __syncthreads();

  // ---- GEMM3: hidden = relu(out_pre(64x256)*Wg1(256x64) + diff*wg1d + bg1); wave w -> cols [16w,16w+16) ----
  {
    f32x4 acc3[4];
    #pragma unroll
    for (int mt = 0; mt < 4; ++mt) acc3[mt] = (f32x4)0.f;
    const bf16x8* pG1 = reinterpret_cast<const bf16x8*>(ws + OFF_G1);
    #pragma unroll
    for (int ks = 0; ks < 8; ++ks) {
      bf16x8 b = pG1[(ks*4 + w)*64 + lane];
      #pragma unroll
      for (int mt = 0; mt < 4; ++mt) {
        bf16x8 a = *reinterpret_cast<const bf16x8*>(&s_regA[((ks*4 + mt)*64 + lane)*8]);
        acc3[mt] = MFMA16(a, b, acc3[mt]);
      }
    }
    int col3 = w*16 + lc;
    float b1v = s_bg1[col3], wdv = s_wg1d[col3];
    #pragma unroll
    for (int mt = 0; mt < 4; ++mt)
      #pragma unroll
      for (int r = 0; r < 4; ++r) {
        int row = mt*16 + lr*4 + r;
        float hv = acc3[mt][r] + b1v + s_diff[row]*wdv;
        hv = fmaxf(hv, 0.f);
        s_hfrag[(((w >> 1)*4 + mt)*64 + 16*((w & 1)*2 + (lc >> 3)) + (lr*4 + r))*8 + (lane & 7)] = (bf16)hv;
      }
  }
  __syncthreads();

  // ---- GEMM4: gate = sigmoid(hidden(64x64)*Wg2(64x256)+bg2); val = out_pre*gate + x ----
  {
    f32x4 acc4[4][4];
    #pragma unroll
    for (int mt = 0; mt < 4; ++mt)
      #pragma unroll
      for (int nt = 0; nt < 4; ++nt) acc4[mt][nt] = (f32x4)0.f;
    const bf16x8* pG2 = reinterpret_cast<const bf16x8*>(ws + OFF_G2);
    #pragma unroll
    for (int ks = 0; ks < 2; ++ks) {
      bf16x8 a[4], bb[4];
      #pragma unroll
      for (int mt = 0; mt < 4; ++mt)
        a[mt] = *reinterpret_cast<const bf16x8*>(&s_hfrag[((ks*4 + mt)*64 + lane)*8]);
      #pragma unroll
      for (int nt = 0; nt < 4; ++nt)
        bb[nt] = pG2[(ks*16 + w*4 + nt)*64 + lane];
      #pragma unroll
      for (int mt = 0; mt < 4; ++mt)
        #pragma unroll
        for (int nt = 0; nt < 4; ++nt)
          acc4[mt][nt] = MFMA16(a[mt], bb[nt], acc4[mt][nt]);
    }
    __syncthreads();   // hfrag reads done before LN scratch (aliased) is written
    const float* xbase = x + (size_t)row0 * D;
    #pragma unroll
    for (int nt = 0; nt < 4; ++nt) {
      int c = w*64 + nt*16 + lc;
      float bg2v = s_bg2[c];
      #pragma unroll
      for (int mt = 0; mt < 4; ++mt)
        #pragma unroll
        for (int r = 0; r < 4; ++r) {
          int row = mt*16 + lr*4 + r;
          float z = acc4[mt][nt][r] + bg2v;
          float gate = fast_rcp(1.f + fast_exp(-z));
          acc2[mt][nt][r] = acc2[mt][nt][r]*gate + xbase[row*D + c];
        }
    }
  }
  // ---- final LN partials (per row over this wave's 64 cols) ----
  {
    #pragma unroll
    for (int mt = 0; mt < 4; ++mt)
      #pragma unroll
      for (int r = 0; r < 4; ++r) {
        float s = 0.f, sq = 0.f;
        #pragma unroll
        for (int nt = 0; nt < 4; ++nt) {
          float v = acc2[mt][nt][r];
          s += v; sq = fmaf(v, v, sq);
        }
        s += __shfl_xor(s, 1, 64);  sq += __shfl_xor(sq, 1, 64);
        s += __shfl_xor(s, 2, 64);  sq += __shfl_xor(sq, 2, 64);
        s += __shfl_xor(s, 4, 64);  sq += __shfl_xor(sq, 4, 64);
        s += __shfl_xor(s, 8, 64);  sq += __shfl_xor(sq, 8, 64);
        if (lc == 0) {
          int row = mt*16 + lr*4 + r;
          s_lnsum[row*4 + w] = s;
          s_lnsq[row*4 + w]  = sq;
        }
      }
  }
  __syncthreads();
  if (t < ROWS) {
    float s  = s_lnsum[t*4] + s_lnsum[t*4+1] + s_lnsum[t*4+2] + s_lnsum[t*4+3];
    float sq = s_lnsq[t*4]  + s_lnsq[t*4+1]  + s_lnsq[t*4+2]  + s_lnsq[t*4+3];
    float mean = s * (1.f/256.f);
    float var  = sq * (1.f/256.f) - mean*mean;
    s_rmean[t] = mean;
    s_rrstd[t] = rsqrtf(var + 1e-5f);
  }
  __syncthreads();
  {
    float* obase = out + (size_t)row0 * D;
    #pragma unroll
    for (int mt = 0; mt < 4; ++mt)
      #pragma unroll
      for (int r = 0; r < 4; ++r) {
        int row = mt*16 + lr*4 + r;
        float mean = s_rmean[row], rstd = s_rrstd[row];
        #pragma unroll
        for (int nt = 0; nt < 4; ++nt) {
          int c = w*64 + nt*16 + lc;
          obase[row*D + c] = (acc2[mt][nt][r] - mean)*rstd*s_lnFg[c] + s_lnFb[c];
        }
      }
  }
}

extern "C" void kernel_launch(void* const* d_in, const int* in_sizes, int n_in,
                              void* d_out, int out_size, void* d_ws, size_t ws_size,
                              hipStream_t stream) {
  (void)in_sizes; (void)n_in; (void)ws_size; (void)out_size;
  const float* x   = (const float*)d_in[0];
  const float* mp  = (const float*)d_in[1];
  const float* Wq  = (const float*)d_in[2];
  const float* bq  = (const float*)d_in[3];
  const float* pk  = (const float*)d_in[4];
  const float* pv  = (const float*)d_in[5];
  const float* imp = (const float*)d_in[6];
  const float* fa  = (const float*)d_in[7];
  const float* ft  = (const float*)d_in[8];
  const float* Wo  = (const float*)d_in[9];
  const float* bo  = (const float*)d_in[10];
  const float* lng = (const float*)d_in[11];
  const float* lnb = (const float*)d_in[12];
  const float* Wf  = (const float*)d_in[13];
  const float* bf  = (const float*)d_in[14];
  const float* Wg1 = (const float*)d_in[15];
  const float* bg1 = (const float*)d_in[16];
  const float* Wg2 = (const float*)d_in[17];
  const float* bg2 = (const float*)d_in[18];
  const float* lnFg= (const float*)d_in[19];
  const float* lnFb= (const float*)d_in[20];
  float* out = (float*)d_out;
  bf16* ws = (bf16*)d_ws;

  hipLaunchKernelGGL(prep_kernel, dim3((NPACK + 255)/256), dim3(256), 0, stream,
                     Wq, Wf, Wg1, Wg2, Wo, ws);
  hipLaunchKernelGGL(faiia_kernel, dim3(NROWS_TOT / ROWS), dim3(256), 0, stream,
                     x, mp, bq, pk, pv, imp, fa, ft, bo, lng, lnb,
                     bf, Wg1, bg1, bg2, lnFg, lnFb, ws, out);
}

// Round 4
// 232.761 us; speedup vs baseline: 1.6103x; 1.6103x over previous
//
#include <hip/hip_runtime.h>
#include <math.h>

typedef __bf16 bf16;
typedef __bf16 bf16x8 __attribute__((ext_vector_type(8)));
typedef float f32x4 __attribute__((ext_vector_type(4)));

#define MFMA16(a,b,c) __builtin_amdgcn_mfma_f32_16x16x32_bf16((a),(b),(c),0,0,0)

#define D 256
#define H 4
#define A 32
#define P 4
#define HA 128
#define RHID 64
#define ROWS 64
#define NROWS_TOT 262144
#define SCALE_F 0.17677669529663687f

// ws offsets in bf16 elements
#define OFF_Q  0
#define OFF_F  32768
#define OFF_G1 65536
#define OFF_G2 81920
#define OFF_O  98304
#define NPACK  102400

__device__ __forceinline__ float fast_exp(float x) { return __expf(x); }
__device__ __forceinline__ float fast_rcp(float x) { return __builtin_amdgcn_rcpf(x); }

// ---------------- weight prepack: f32 -> bf16 in MFMA B-fragment order ----------------
// B-fragment for 16x16x32: lane l holds col n = l&15, k = (l>>4)*8 + j (j=0..7, contiguous)
__global__ __launch_bounds__(256)
void prep_kernel(const float* __restrict__ Wq, const float* __restrict__ Wf,
                 const float* __restrict__ Wg1, const float* __restrict__ Wg2,
                 const float* __restrict__ Wo, bf16* __restrict__ ws)
{
  int i = blockIdx.x * 256 + threadIdx.x;
  if (i >= NPACK) return;
  float v;
  if (i < OFF_F) {              // packQ [h(4)][ks(8)][nt(2)][l(64)][j(8)], K=256,N=32 per head
    int j = i & 7, l = (i >> 3) & 63, nt = (i >> 9) & 1, ks = (i >> 10) & 7, h = i >> 13;
    int k = ks * 32 + (l >> 4) * 8 + j, n = nt * 16 + (l & 15);
    v = Wq[(h * 256 + k) * 32 + n];
  } else if (i < OFF_G1) {      // packF [ks(4)][gnt(16)][l][j], K=128,N=256
    int ii = i - OFF_F;
    int j = ii & 7, l = (ii >> 3) & 63, g = (ii >> 9) & 15, ks = ii >> 13;
    int k = ks * 32 + (l >> 4) * 8 + j, n = g * 16 + (l & 15);
    v = Wf[k * 256 + n];
  } else if (i < OFF_G2) {      // packG1 [ks(8)][nt(4)][l][j], K=256,N=64 (row 256 added via s_wg1d)
    int ii = i - OFF_G1;
    int j = ii & 7, l = (ii >> 3) & 63, nt = (ii >> 9) & 3, ks = ii >> 11;
    int k = ks * 32 + (l >> 4) * 8 + j, n = nt * 16 + (l & 15);
    v = Wg1[k * 64 + n];
  } else if (i < OFF_O) {       // packG2 [ks(2)][gnt(16)][l][j], K=64,N=256
    int ii = i - OFF_G2;
    int j = ii & 7, l = (ii >> 3) & 63, g = (ii >> 9) & 15, ks = ii >> 13;
    int k = ks * 32 + (l >> 4) * 8 + j, n = g * 16 + (l & 15);
    v = Wg2[k * 256 + n];
  } else {                      // packO [h(4)][nt(2)][l][j], K=32,N=32 per head
    int ii = i - OFF_O;
    int j = ii & 7, l = (ii >> 3) & 63, nt = (ii >> 9) & 1, h = ii >> 10;
    int k = (l >> 4) * 8 + j, n = nt * 16 + (l & 15);
    v = Wo[(h * 32 + k) * 32 + n];
  }
  ws[i] = (bf16)v;
}

// ---------------- fused main kernel: 64 rows/block, 4 waves, 5 MFMA GEMMs ----------------
// LDS ~52 KB -> 3 blocks/CU by LDS; keep VGPR <= 128 (no forced cap -> no spills).
__global__ __launch_bounds__(256, 2)
void faiia_kernel(const float* __restrict__ x, const float* __restrict__ mp,
    const float* __restrict__ bq, const float* __restrict__ pk,
    const float* __restrict__ pv, const float* __restrict__ imp,
    const float* __restrict__ fa, const float* __restrict__ ft,
    const float* __restrict__ bo, const float* __restrict__ lng,
    const float* __restrict__ lnb, const float* __restrict__ bfb,
    const float* __restrict__ Wg1, const float* __restrict__ bg1,
    const float* __restrict__ bg2, const float* __restrict__ lnFg,
    const float* __restrict__ lnFb, const bf16* __restrict__ ws,
    float* __restrict__ out)
{
  // region A (32KB), multi-use:
  //   [stage]   xfrag   [mt4][ks8][64][8]                (full 32KB)
  //   [GEMM1->B] s_q    upper 16KB: row-major 64x128 bf16, XOR-swizzled
  //   [B->Wo]   attfrag [h4][mt4][64][8]                 (lower 16KB)
  //   [Wo->G2]  combfrag [ks2:4][mt4][64][8]             (upper 16KB)
  //   [G2->G3]  opfrag  [ks3:8][mt4][64][8]              (full 32KB)
  __shared__ __attribute__((aligned(16))) bf16 s_regA[16384];
  __shared__ __attribute__((aligned(16))) bf16 s_hfrag[4096];   // hidden frag; later LN scratch (f32)
  __shared__ float s_pk[H*P*A], s_pv[H*P*A], s_imp[H*P], s_fa[H], s_ft[H];
  __shared__ float s_bq[HA], s_bo[HA], s_lng[HA], s_lnb[HA];
  __shared__ float s_bf[D], s_bg1[RHID], s_wg1d[RHID], s_bg2[D], s_lnFg[D], s_lnFb[D];
  __shared__ float s_diff[ROWS];

  bf16* s_q = s_regA + 8192;                 // aliases upper 16KB of region A
  float* s_lnsum = reinterpret_cast<float*>(s_hfrag);        // 256 f32
  float* s_lnsq  = s_lnsum + 256;                            // 256 f32
  float* s_rmean = s_lnsq + 256;                             // 64 f32
  float* s_rrstd = s_rmean + 64;                             // 64 f32

  const int t = threadIdx.x;
  const int lane = t & 63;
  const int w = t >> 6;           // wave id
  const int lr = lane >> 4;       // row-group 0..3
  const int lc = lane & 15;       // col-in-tile
  const int row0 = blockIdx.x * ROWS;

  // ---- stage small constants ----
  for (int i = t; i < H*P*A; i += 256) { s_pk[i] = pk[i]; s_pv[i] = pv[i]; }
  if (t < H*P) s_imp[t] = imp[t];
  if (t < H) { s_fa[t] = fa[t]; s_ft[t] = ft[t]; }
  if (t < HA) { s_bq[t] = bq[t]; s_bo[t] = bo[t]; s_lng[t] = lng[t]; s_lnb[t] = lnb[t]; }
  s_bf[t] = bfb[t]; s_bg2[t] = bg2[t]; s_lnFg[t] = lnFg[t]; s_lnFb[t] = lnFb[t];
  if (t < RHID) { s_bg1[t] = bg1[t]; s_wg1d[t] = Wg1[256*RHID + t]; }
  if (t < ROWS) { float m = mp[row0 + t]; s_diff[t] = 1.f - 2.f*fabsf(m - 0.5f); }

  // ---- stage x -> bf16 A-fragments: slot s = (mt*8+ks)*64 + l ----
  {
    const float* xbase = x + (size_t)row0 * D;
    #pragma unroll
    for (int i = 0; i < 8; ++i) {
      int s = t + 256*i;
      int l = s & 63, ks = (s >> 6) & 7, mt = s >> 9;
      int row = mt*16 + (l & 15);
      int k0 = ks*32 + ((l >> 4) & 3)*8;
      const float* xp = xbase + row*D + k0;
      float4 v0 = *reinterpret_cast<const float4*>(xp);
      float4 v1 = *reinterpret_cast<const float4*>(xp + 4);
      bf16x8 fr;
      fr[0]=(bf16)v0.x; fr[1]=(bf16)v0.y; fr[2]=(bf16)v0.z; fr[3]=(bf16)v0.w;
      fr[4]=(bf16)v1.x; fr[5]=(bf16)v1.y; fr[6]=(bf16)v1.z; fr[7]=(bf16)v1.w;
      *reinterpret_cast<bf16x8*>(&s_regA[(size_t)s * 8]) = fr;
    }
  }
  __syncthreads();

  // ---- GEMM1: Q = X(64x256) * Wq[head=w](256x32); wave w computes head w ----
  {
    f32x4 acc[4][2];
    #pragma unroll
    for (int mt = 0; mt < 4; ++mt) { acc[mt][0] = (f32x4)0.f; acc[mt][1] = (f32x4)0.f; }
    const bf16x8* pQ = reinterpret_cast<const bf16x8*>(ws + OFF_Q);
    #pragma unroll
    for (int ks = 0; ks < 8; ++ks) {
      bf16x8 b0 = pQ[((w*8 + ks)*2 + 0)*64 + lane];
      bf16x8 b1 = pQ[((w*8 + ks)*2 + 1)*64 + lane];
      #pragma unroll
      for (int mt = 0; mt < 4; ++mt) {
        bf16x8 a = *reinterpret_cast<const bf16x8*>(&s_regA[((mt*8 + ks)*64 + lane)*8]);
        acc[mt][0] = MFMA16(a, b0, acc[mt][0]);
        acc[mt][1] = MFMA16(a, b1, acc[mt][1]);
      }
    }
    __syncthreads();   // all xfrag reads done before s_q overwrites upper 16KB
    float bq0 = s_bq[w*32 + lc], bq1 = s_bq[w*32 + 16 + lc];
    #pragma unroll
    for (int mt = 0; mt < 4; ++mt)
      #pragma unroll
      for (int r = 0; r < 4; ++r) {
        int row = mt*16 + lr*4 + r;
        int sw = (row & 7) << 3;                 // XOR swizzle (in bf16 elements)
        int c0 = (w*32 + lc) ^ sw;
        int c1 = (w*32 + 16 + lc) ^ sw;
        s_q[row*128 + c0] = (bf16)(acc[mt][0][r] + bq0);
        s_q[row*128 + c1] = (bf16)(acc[mt][1][r] + bq1);
      }
  }
  __syncthreads();

  // ---- Phase B: prototype attention, thread = (row, head); writes attfrag (lower 16KB) ----
  {
    const int r = t >> 2, h = t & 3;
    const int swr = (r & 7) << 3;
    float q[32];
    #pragma unroll
    for (int g = 0; g < 4; ++g) {
      int c0 = (h*32 + g*8) ^ swr;               // 8-aligned: swizzle only flips bits >=3
      bf16x8 v = *reinterpret_cast<const bf16x8*>(&s_q[r*128 + c0]);
      #pragma unroll
      for (int j = 0; j < 8; ++j) q[g*8 + j] = (float)v[j];
    }
    float u = s_diff[r];
    float up = u + 1e-8f;
    float mod = 1.f + s_fa[h]*up*up*s_ft[h];
    float sc[4];
    #pragma unroll
    for (int p = 0; p < 4; ++p) {
      float s = s_imp[h*4 + p];
      const float4* kp = reinterpret_cast<const float4*>(&s_pk[(h*4 + p)*32]);
      #pragma unroll
      for (int g = 0; g < 8; ++g) {
        float4 kv = kp[g];
        s = fmaf(q[g*4+0], kv.x, s); s = fmaf(q[g*4+1], kv.y, s);
        s = fmaf(q[g*4+2], kv.z, s); s = fmaf(q[g*4+3], kv.w, s);
      }
      sc[p] = s * mod * SCALE_F;
    }
    float mx = fmaxf(fmaxf(sc[0], sc[1]), fmaxf(sc[2], sc[3]));
    float e0 = fast_exp(sc[0]-mx), e1 = fast_exp(sc[1]-mx);
    float e2 = fast_exp(sc[2]-mx), e3 = fast_exp(sc[3]-mx);
    float inv = fast_rcp(e0+e1+e2+e3);
    e0 *= inv; e1 *= inv; e2 *= inv; e3 *= inv;
    const float4* p0 = reinterpret_cast<const float4*>(&s_pv[(h*4+0)*32]);
    const float4* p1 = reinterpret_cast<const float4*>(&s_pv[(h*4+1)*32]);
    const float4* p2 = reinterpret_cast<const float4*>(&s_pv[(h*4+2)*32]);
    const float4* p3 = reinterpret_cast<const float4*>(&s_pv[(h*4+3)*32]);
    const int mt = r >> 4, rl = r & 15;
    #pragma unroll
    for (int g = 0; g < 4; ++g) {
      float4 a0 = p0[g*2],   b0v = p0[g*2+1];
      float4 a1 = p1[g*2],   b1v = p1[g*2+1];
      float4 a2 = p2[g*2],   b2v = p2[g*2+1];
      float4 a3 = p3[g*2],   b3v = p3[g*2+1];
      bf16x8 av;
      av[0] = (bf16)(e0*a0.x + e1*a1.x + e2*a2.x + e3*a3.x);
      av[1] = (bf16)(e0*a0.y + e1*a1.y + e2*a2.y + e3*a3.y);
      av[2] = (bf16)(e0*a0.z + e1*a1.z + e2*a2.z + e3*a3.z);
      av[3] = (bf16)(e0*a0.w + e1*a1.w + e2*a2.w + e3*a3.w);
      av[4] = (bf16)(e0*b0v.x + e1*b1v.x + e2*b2v.x + e3*b3v.x);
      av[5] = (bf16)(e0*b0v.y + e1*b1v.y + e2*b2v.y + e3*b3v.y);
      av[6] = (bf16)(e0*b0v.z + e1*b1v.z + e2*b2v.z + e3*b3v.z);
      av[7] = (bf16)(e0*b0v.w + e1*b1v.w + e2*b2v.w + e3*b3v.w);
      *reinterpret_cast<bf16x8*>(&s_regA[(((h*4) + mt)*64 + g*16 + rl)*8]) = av;
    }
  }
  __syncthreads();

  // ---- Wo-GEMM + per-head LN; wave w = head w; writes combfrag (upper 16KB, over dead s_q) ----
  {
    f32x4 acc[4][2];
    #pragma unroll
    for (int mt = 0; mt < 4; ++mt) { acc[mt][0] = (f32x4)0.f; acc[mt][1] = (f32x4)0.f; }
    const bf16x8* pO = reinterpret_cast<const bf16x8*>(ws + OFF_O);
    bf16x8 b0 = pO[(w*2 + 0)*64 + lane];
    bf16x8 b1 = pO[(w*2 + 1)*64 + lane];
    #pragma unroll
    for (int mt = 0; mt < 4; ++mt) {
      bf16x8 a = *reinterpret_cast<const bf16x8*>(&s_regA[((w*4 + mt)*64 + lane)*8]);
      acc[mt][0] = MFMA16(a, b0, acc[mt][0]);
      acc[mt][1] = MFMA16(a, b1, acc[mt][1]);
    }
    float bo0 = s_bo[w*32 + lc],  bo1 = s_bo[w*32 + 16 + lc];
    float lg0 = s_lng[w*32 + lc], lg1 = s_lng[w*32 + 16 + lc];
    float lb0 = s_lnb[w*32 + lc], lb1 = s_lnb[w*32 + 16 + lc];
    #pragma unroll
    for (int mt = 0; mt < 4; ++mt)
      #pragma unroll
      for (int r = 0; r < 4; ++r) {
        float v0 = acc[mt][0][r] + bo0;
        float v1 = acc[mt][1][r] + bo1;
        float s = v0 + v1, sq = v0*v0 + v1*v1;
        s += __shfl_xor(s, 1, 64);  sq += __shfl_xor(sq, 1, 64);
        s += __shfl_xor(s, 2, 64);  sq += __shfl_xor(sq, 2, 64);
        s += __shfl_xor(s, 4, 64);  sq += __shfl_xor(sq, 4, 64);
        s += __shfl_xor(s, 8, 64);  sq += __shfl_xor(sq, 8, 64);
        float mean = s * (1.f/32.f);
        float var  = sq * (1.f/32.f) - mean*mean;
        float rstd = rsqrtf(var + 1e-5f);
        float n0 = (v0 - mean)*rstd*lg0 + lb0;
        float n1 = (v1 - mean)*rstd*lg1 + lb1;
        int rl = lr*4 + r;
        int base = 8192 + ((w*4 + mt)*64)*8;
        s_regA[base + (16*(lc >> 3)       + rl)*8 + (lane & 7)] = (bf16)n0;
        s_regA[base + (16*(2 + (lc >> 3)) + rl)*8 + (lane & 7)] = (bf16)n1;
      }
  }
  __syncthreads();

  // ---- GEMM2: out_pre = combined(64x128) * Wf(128x256); wave w -> cols [64w,64w+64) ----
  f32x4 acc2[4][4];
  {
    #pragma unroll
    for (int mt = 0; mt < 4; ++mt)
      #pragma unroll
      for (int nt = 0; nt < 4; ++nt) acc2[mt][nt] = (f32x4)0.f;
    const bf16x8* pF = reinterpret_cast<const bf16x8*>(ws + OFF_F);
    #pragma unroll
    for (int ks = 0; ks < 4; ++ks) {
      bf16x8 a[4], bb[4];
      #pragma unroll
      for (int mt = 0; mt < 4; ++mt)
        a[mt] = *reinterpret_cast<const bf16x8*>(&s_regA[8192 + ((ks*4 + mt)*64 + lane)*8]);
      #pragma unroll
      for (int nt = 0; nt < 4; ++nt)
        bb[nt] = pF[(ks*16 + w*4 + nt)*64 + lane];
      #pragma unroll
      for (int mt = 0; mt < 4; ++mt)
        #pragma unroll
        for (int nt = 0; nt < 4; ++nt)
          acc2[mt][nt] = MFMA16(a[mt], bb[nt], acc2[mt][nt]);
    }
    #pragma unroll
    for (int nt = 0; nt < 4; ++nt) {
      float bfv = s_bf[w*64 + nt*16 + lc];
      #pragma unroll
      for (int mt = 0; mt < 4; ++mt)
        #pragma unroll
        for (int r = 0; r < 4; ++r) acc2[mt][nt][r] += bfv;
    }
  }
  __syncthreads();   // all combfrag reads done before opfrag overwrites region A
  {
    #pragma unroll
    for (int mt = 0; mt < 4; ++mt)
      #pragma unroll
      for (int nt = 0; nt < 4; ++nt) {
        int ks3 = w*2 + (nt >> 1);
        #pragma unroll
        for (int r = 0; r < 4; ++r) {
          int lane2 = 16*((nt & 1)*2 + (lc >> 3)) + (lr*4 + r);
          s_regA[((ks3*4 + mt)*64 + lane2)*8 + (lane & 7)] = (bf16)acc2[mt][nt][r];
        }
      }
  }
  __syncthreads();

  // ---- GEMM3: hidden = relu(out_pre(64x256)*Wg1(256x64) + diff*wg1d + bg1); wave w -> cols [16w,16w+16) ----
  {
    f32x4 acc3[4];
    #pragma unroll
    for (int mt = 0; mt < 4; ++mt) acc3[mt] = (f32x4)0.f;
    const bf16x8* pG1 = reinterpret_cast<const bf16x8*>(ws + OFF_G1);
    #pragma unroll
    for (int ks = 0; ks < 8; ++ks) {
      bf16x8 b = pG1[(ks*4 + w)*64 + lane];
      #pragma unroll
      for (int mt = 0; mt < 4; ++mt) {
        bf16x8 a = *reinterpret_cast<const bf16x8*>(&s_regA[((ks*4 + mt)*64 + lane)*8]);
        acc3[mt] = MFMA16(a, b, acc3[mt]);
      }
    }
    int col3 = w*16 + lc;
    float b1v = s_bg1[col3], wdv = s_wg1d[col3];
    #pragma unroll
    for (int mt = 0; mt < 4; ++mt)
      #pragma unroll
      for (int r = 0; r < 4; ++r) {
        int row = mt*16 + lr*4 + r;
        float hv = acc3[mt][r] + b1v + s_diff[row]*wdv;
        hv = fmaxf(hv, 0.f);
        s_hfrag[(((w >> 1)*4 + mt)*64 + 16*((w & 1)*2 + (lc >> 3)) + (lr*4 + r))*8 + (lane & 7)] = (bf16)hv;
      }
  }
  __syncthreads();

  // ---- GEMM4 (two nt-halves to cap live registers): gate = sigmoid(...); val = out_pre*gate + x ----
  {
    const float* xbase = x + (size_t)row0 * D;
    const bf16x8* pG2 = reinterpret_cast<const bf16x8*>(ws + OFF_G2);
    #pragma unroll
    for (int half = 0; half < 2; ++half) {
      f32x4 acc4[4][2];
      #pragma unroll
      for (int mt = 0; mt < 4; ++mt) { acc4[mt][0] = (f32x4)0.f; acc4[mt][1] = (f32x4)0.f; }
      #pragma unroll
      for (int ks = 0; ks < 2; ++ks) {
        bf16x8 a[4], bb[2];
        #pragma unroll
        for (int mt = 0; mt < 4; ++mt)
          a[mt] = *reinterpret_cast<const bf16x8*>(&s_hfrag[((ks*4 + mt)*64 + lane)*8]);
        #pragma unroll
        for (int n2 = 0; n2 < 2; ++n2)
          bb[n2] = pG2[(ks*16 + w*4 + half*2 + n2)*64 + lane];
        #pragma unroll
        for (int mt = 0; mt < 4; ++mt)
          #pragma unroll
          for (int n2 = 0; n2 < 2; ++n2)
            acc4[mt][n2] = MFMA16(a[mt], bb[n2], acc4[mt][n2]);
      }
      #pragma unroll
      for (int n2 = 0; n2 < 2; ++n2) {
        int nt = half*2 + n2;
        int c = w*64 + nt*16 + lc;
        float bg2v = s_bg2[c];
        #pragma unroll
        for (int mt = 0; mt < 4; ++mt)
          #pragma unroll
          for (int r = 0; r < 4; ++r) {
            int row = mt*16 + lr*4 + r;
            float z = acc4[mt][n2][r] + bg2v;
            float gate = fast_rcp(1.f + fast_exp(-z));
            acc2[mt][nt][r] = acc2[mt][nt][r]*gate + xbase[row*D + c];
          }
      }
    }
  }
  __syncthreads();   // all hfrag reads done before LN scratch (aliased) is written

  // ---- final LN partials (per row over this wave's 64 cols) ----
  {
    #pragma unroll
    for (int mt = 0; mt < 4; ++mt)
      #pragma unroll
      for (int r = 0; r < 4; ++r) {
        float s = 0.f, sq = 0.f;
        #pragma unroll
        for (int nt = 0; nt < 4; ++nt) {
          float v = acc2[mt][nt][r];
          s += v; sq = fmaf(v, v, sq);
        }
        s += __shfl_xor(s, 1, 64);  sq += __shfl_xor(sq, 1, 64);
        s += __shfl_xor(s, 2, 64);  sq += __shfl_xor(sq, 2, 64);
        s += __shfl_xor(s, 4, 64);  sq += __shfl_xor(sq, 4, 64);
        s += __shfl_xor(s, 8, 64);  sq += __shfl_xor(sq, 8, 64);
        if (lc == 0) {
          int row = mt*16 + lr*4 + r;
          s_lnsum[row*4 + w] = s;
          s_lnsq[row*4 + w]  = sq;
        }
      }
  }
  __syncthreads();
  if (t < ROWS) {
    float s  = s_lnsum[t*4] + s_lnsum[t*4+1] + s_lnsum[t*4+2] + s_lnsum[t*4+3];
    float sq = s_lnsq[t*4]  + s_lnsq[t*4+1]  + s_lnsq[t*4+2]  + s_lnsq[t*4+3];
    float mean = s * (1.f/256.f);
    float var  = sq * (1.f/256.f) - mean*mean;
    s_rmean[t] = mean;
    s_rrstd[t] = rsqrtf(var + 1e-5f);
  }
  __syncthreads();
  {
    float* obase = out + (size_t)row0 * D;
    #pragma unroll
    for (int mt = 0; mt < 4; ++mt)
      #pragma unroll
      for (int r = 0; r < 4; ++r) {
        int row = mt*16 + lr*4 + r;
        float mean = s_rmean[row], rstd = s_rrstd[row];
        #pragma unroll
        for (int nt = 0; nt < 4; ++nt) {
          int c = w*64 + nt*16 + lc;
          obase[row*D + c] = (acc2[mt][nt][r] - mean)*rstd*s_lnFg[c] + s_lnFb[c];
        }
      }
  }
}

extern "C" void kernel_launch(void* const* d_in, const int* in_sizes, int n_in,
                              void* d_out, int out_size, void* d_ws, size_t ws_size,
                              hipStream_t stream) {
  (void)in_sizes; (void)n_in; (void)ws_size; (void)out_size;
  const float* x   = (const float*)d_in[0];
  const float* mp  = (const float*)d_in[1];
  const float* Wq  = (const float*)d_in[2];
  const float* bq  = (const float*)d_in[3];
  const float* pk  = (const float*)d_in[4];
  const float* pv  = (const float*)d_in[5];
  const float* imp = (const float*)d_in[6];
  const float* fa  = (const float*)d_in[7];
  const float* ft  = (const float*)d_in[8];
  const float* Wo  = (const float*)d_in[9];
  const float* bo  = (const float*)d_in[10];
  const float* lng = (const float*)d_in[11];
  const float* lnb = (const float*)d_in[12];
  const float* Wf  = (const float*)d_in[13];
  const float* bf  = (const float*)d_in[14];
  const float* Wg1 = (const float*)d_in[15];
  const float* bg1 = (const float*)d_in[16];
  const float* Wg2 = (const float*)d_in[17];
  const float* bg2 = (const float*)d_in[18];
  const float* lnFg= (const float*)d_in[19];
  const float* lnFb= (const float*)d_in[20];
  float* out = (float*)d_out;
  bf16* ws = (bf16*)d_ws;

  hipLaunchKernelGGL(prep_kernel, dim3((NPACK + 255)/256), dim3(256), 0, stream,
                     Wq, Wf, Wg1, Wg2, Wo, ws);
  hipLaunchKernelGGL(faiia_kernel, dim3(NROWS_TOT / ROWS), dim3(256), 0, stream,
                     x, mp, bq, pk, pv, imp, fa, ft, bo, lng, lnb,
                     bf, Wg1, bg1, bg2, lnFg, lnFb, ws, out);
}

// Round 5
// 229.733 us; speedup vs baseline: 1.6315x; 1.0132x over previous
//
#include <hip/hip_runtime.h>
#include <math.h>

typedef __bf16 bf16;
typedef __bf16 bf16x8 __attribute__((ext_vector_type(8)));
typedef float f32x4 __attribute__((ext_vector_type(4)));

#define MFMA16(a,b,c) __builtin_amdgcn_mfma_f32_16x16x32_bf16((a),(b),(c),0,0,0)

#define D 256
#define H 4
#define A 32
#define P 4
#define HA 128
#define RHID 64
#define ROWS 64
#define NROWS_TOT 262144
#define SCALE_F 0.17677669529663687f

// ws offsets in bf16 elements
#define OFF_Q  0
#define OFF_F  32768
#define OFF_G1 65536
#define OFF_G2 81920
#define OFF_O  98304
#define NPACK  102400

__device__ __forceinline__ float fast_exp(float x) { return __expf(x); }
__device__ __forceinline__ float fast_rcp(float x) { return __builtin_amdgcn_rcpf(x); }

// ---------------- weight prepack: f32 -> bf16 in MFMA B-fragment order ----------------
// B-fragment for 16x16x32: lane l holds col n = l&15, k = (l>>4)*8 + j (j=0..7, contiguous)
__global__ __launch_bounds__(256)
void prep_kernel(const float* __restrict__ Wq, const float* __restrict__ Wf,
                 const float* __restrict__ Wg1, const float* __restrict__ Wg2,
                 const float* __restrict__ Wo, bf16* __restrict__ ws)
{
  int i = blockIdx.x * 256 + threadIdx.x;
  if (i >= NPACK) return;
  float v;
  if (i < OFF_F) {              // packQ [h(4)][ks(8)][nt(2)][l(64)][j(8)], K=256,N=32 per head
    int j = i & 7, l = (i >> 3) & 63, nt = (i >> 9) & 1, ks = (i >> 10) & 7, h = i >> 13;
    int k = ks * 32 + (l >> 4) * 8 + j, n = nt * 16 + (l & 15);
    v = Wq[(h * 256 + k) * 32 + n];
  } else if (i < OFF_G1) {      // packF [ks(4)][gnt(16)][l][j], K=128,N=256
    int ii = i - OFF_F;
    int j = ii & 7, l = (ii >> 3) & 63, g = (ii >> 9) & 15, ks = ii >> 13;
    int k = ks * 32 + (l >> 4) * 8 + j, n = g * 16 + (l & 15);
    v = Wf[k * 256 + n];
  } else if (i < OFF_G2) {      // packG1 [ks(8)][nt(4)][l][j], K=256,N=64 (row 256 added via s_wg1d)
    int ii = i - OFF_G1;
    int j = ii & 7, l = (ii >> 3) & 63, nt = (ii >> 9) & 3, ks = ii >> 11;
    int k = ks * 32 + (l >> 4) * 8 + j, n = nt * 16 + (l & 15);
    v = Wg1[k * 64 + n];
  } else if (i < OFF_O) {       // packG2 [ks(2)][gnt(16)][l][j], K=64,N=256
    int ii = i - OFF_G2;
    int j = ii & 7, l = (ii >> 3) & 63, g = (ii >> 9) & 15, ks = ii >> 13;
    int k = ks * 32 + (l >> 4) * 8 + j, n = g * 16 + (l & 15);
    v = Wg2[k * 256 + n];
  } else {                      // packO [h(4)][nt(2)][l][j], K=32,N=32 per head
    int ii = i - OFF_O;
    int j = ii & 7, l = (ii >> 3) & 63, nt = (ii >> 9) & 1, h = ii >> 10;
    int k = (l >> 4) * 8 + j, n = nt * 16 + (l & 15);
    v = Wo[(h * 32 + k) * 32 + n];
  }
  ws[i] = (bf16)v;
}

// ---------------- fused main kernel: 64 rows/block, 4 waves, 5 MFMA GEMMs ----------------
// LDS ~40.5 KB -> target 4 blocks/CU (16 waves, VGPR=128 exactly allows it).
__global__ __launch_bounds__(256, 2)
void faiia_kernel(const float* __restrict__ x, const float* __restrict__ mp,
    const float* __restrict__ bq, const float* __restrict__ pk,
    const float* __restrict__ pv, const float* __restrict__ imp,
    const float* __restrict__ fa, const float* __restrict__ ft,
    const float* __restrict__ bo, const float* __restrict__ lng,
    const float* __restrict__ lnb, const float* __restrict__ bfb,
    const float* __restrict__ Wg1, const float* __restrict__ bg1,
    const float* __restrict__ bg2, const float* __restrict__ lnFg,
    const float* __restrict__ lnFb, const bf16* __restrict__ ws,
    float* __restrict__ out)
{
  // region A (32KB), multi-use timeline:
  //   xfrag(full) -> s_q(upper, swizzled) -> attfrag(lower) -> combfrag(upper)
  //   -> opfrag(full) -> hidden frag (bytes 0..8191) + LN scratch (bytes 8192..10751)
  __shared__ __attribute__((aligned(16))) bf16 s_regA[16384];
  __shared__ float s_pk[H*P*A], s_pv[H*P*A], s_imp[H*P], s_fa[H], s_ft[H];
  __shared__ bf16 s_bq[HA], s_bo[HA], s_lng[HA], s_lnb[HA];
  __shared__ bf16 s_bf[D], s_bg2[D], s_lnFg[D], s_lnFb[D];
  __shared__ float s_bg1[RHID], s_wg1d[RHID];
  __shared__ float s_diff[ROWS];

  bf16* s_q = s_regA + 8192;                                // upper 16KB of region A
  float* s_lnsum = reinterpret_cast<float*>(s_regA + 4096); // bytes 8192.. (dead during GEMM4)
  float* s_lnsq  = s_lnsum + 256;
  float* s_rmean = s_lnsq + 256;
  float* s_rrstd = s_rmean + 64;

  const int t = threadIdx.x;
  const int lane = t & 63;
  const int w = t >> 6;           // wave id
  const int lr = lane >> 4;       // row-group 0..3
  const int lc = lane & 15;       // col-in-tile
  const int row0 = blockIdx.x * ROWS;

  // ---- stage small constants ----
  for (int i = t; i < H*P*A; i += 256) { s_pk[i] = pk[i]; s_pv[i] = pv[i]; }
  if (t < H*P) s_imp[t] = imp[t];
  if (t < H) { s_fa[t] = fa[t]; s_ft[t] = ft[t]; }
  if (t < HA) { s_bq[t] = (bf16)bq[t]; s_bo[t] = (bf16)bo[t];
                s_lng[t] = (bf16)lng[t]; s_lnb[t] = (bf16)lnb[t]; }
  s_bf[t] = (bf16)bfb[t]; s_bg2[t] = (bf16)bg2[t];
  s_lnFg[t] = (bf16)lnFg[t]; s_lnFb[t] = (bf16)lnFb[t];
  if (t < RHID) { s_bg1[t] = bg1[t]; s_wg1d[t] = Wg1[256*RHID + t]; }
  if (t < ROWS) { float m = mp[row0 + t]; s_diff[t] = 1.f - 2.f*fabsf(m - 0.5f); }

  // ---- stage x -> bf16 A-fragments: slot s = (mt*8+ks)*64 + l ----
  {
    const float* xbase = x + (size_t)row0 * D;
    #pragma unroll
    for (int i = 0; i < 8; ++i) {
      int s = t + 256*i;
      int l = s & 63, ks = (s >> 6) & 7, mt = s >> 9;
      int row = mt*16 + (l & 15);
      int k0 = ks*32 + ((l >> 4) & 3)*8;
      const float* xp = xbase + row*D + k0;
      float4 v0 = *reinterpret_cast<const float4*>(xp);
      float4 v1 = *reinterpret_cast<const float4*>(xp + 4);
      bf16x8 fr;
      fr[0]=(bf16)v0.x; fr[1]=(bf16)v0.y; fr[2]=(bf16)v0.z; fr[3]=(bf16)v0.w;
      fr[4]=(bf16)v1.x; fr[5]=(bf16)v1.y; fr[6]=(bf16)v1.z; fr[7]=(bf16)v1.w;
      *reinterpret_cast<bf16x8*>(&s_regA[(size_t)s * 8]) = fr;
    }
  }
  __syncthreads();

  // ---- GEMM1: Q = X(64x256) * Wq[head=w](256x32); wave w computes head w ----
  {
    f32x4 acc[4][2];
    #pragma unroll
    for (int mt = 0; mt < 4; ++mt) { acc[mt][0] = (f32x4)0.f; acc[mt][1] = (f32x4)0.f; }
    const bf16x8* pQ = reinterpret_cast<const bf16x8*>(ws + OFF_Q);
    #pragma unroll
    for (int ks = 0; ks < 8; ++ks) {
      bf16x8 b0 = pQ[((w*8 + ks)*2 + 0)*64 + lane];
      bf16x8 b1 = pQ[((w*8 + ks)*2 + 1)*64 + lane];
      #pragma unroll
      for (int mt = 0; mt < 4; ++mt) {
        bf16x8 a = *reinterpret_cast<const bf16x8*>(&s_regA[((mt*8 + ks)*64 + lane)*8]);
        acc[mt][0] = MFMA16(a, b0, acc[mt][0]);
        acc[mt][1] = MFMA16(a, b1, acc[mt][1]);
      }
    }
    __syncthreads();   // all xfrag reads done before s_q overwrites upper 16KB
    float bq0 = (float)s_bq[w*32 + lc], bq1 = (float)s_bq[w*32 + 16 + lc];
    #pragma unroll
    for (int mt = 0; mt < 4; ++mt)
      #pragma unroll
      for (int r = 0; r < 4; ++r) {
        int row = mt*16 + lr*4 + r;
        int sw = (row & 7) << 3;                 // XOR swizzle (bf16 elements)
        int c0 = (w*32 + lc) ^ sw;
        int c1 = (w*32 + 16 + lc) ^ sw;
        s_q[row*128 + c0] = (bf16)(acc[mt][0][r] + bq0);
        s_q[row*128 + c1] = (bf16)(acc[mt][1][r] + bq1);
      }
  }
  __syncthreads();

  // ---- Phase B: prototype attention; wave w = head w, lane = row ----
  // pk/pv reads are wave-uniform (broadcast); q reads swizzle-spread across banks.
  {
    const int r = lane;
    const int h = w;
    const int swr = (r & 7) << 3;
    float q[32];
    #pragma unroll
    for (int g = 0; g < 4; ++g) {
      int c0 = (h*32 + g*8) ^ swr;               // 8-aligned: XOR flips bits >=3 only
      bf16x8 v = *reinterpret_cast<const bf16x8*>(&s_q[r*128 + c0]);
      #pragma unroll
      for (int j = 0; j < 8; ++j) q[g*8 + j] = (float)v[j];
    }
    float u = s_diff[r];
    float up = u + 1e-8f;
    float mod = 1.f + s_fa[h]*up*up*s_ft[h];
    float sc[4];
    #pragma unroll
    for (int p = 0; p < 4; ++p) {
      float s = s_imp[h*4 + p];
      const float4* kp = reinterpret_cast<const float4*>(&s_pk[(h*4 + p)*32]);
      #pragma unroll
      for (int g = 0; g < 8; ++g) {
        float4 kv = kp[g];
        s = fmaf(q[g*4+0], kv.x, s); s = fmaf(q[g*4+1], kv.y, s);
        s = fmaf(q[g*4+2], kv.z, s); s = fmaf(q[g*4+3], kv.w, s);
      }
      sc[p] = s * mod * SCALE_F;
    }
    float mx = fmaxf(fmaxf(sc[0], sc[1]), fmaxf(sc[2], sc[3]));
    float e0 = fast_exp(sc[0]-mx), e1 = fast_exp(sc[1]-mx);
    float e2 = fast_exp(sc[2]-mx), e3 = fast_exp(sc[3]-mx);
    float inv = fast_rcp(e0+e1+e2+e3);
    e0 *= inv; e1 *= inv; e2 *= inv; e3 *= inv;
    const float4* p0 = reinterpret_cast<const float4*>(&s_pv[(h*4+0)*32]);
    const float4* p1 = reinterpret_cast<const float4*>(&s_pv[(h*4+1)*32]);
    const float4* p2 = reinterpret_cast<const float4*>(&s_pv[(h*4+2)*32]);
    const float4* p3 = reinterpret_cast<const float4*>(&s_pv[(h*4+3)*32]);
    const int mt = r >> 4, rl = r & 15;
    #pragma unroll
    for (int g = 0; g < 4; ++g) {
      float4 a0 = p0[g*2],   b0v = p0[g*2+1];
      float4 a1 = p1[g*2],   b1v = p1[g*2+1];
      float4 a2 = p2[g*2],   b2v = p2[g*2+1];
      float4 a3 = p3[g*2],   b3v = p3[g*2+1];
      bf16x8 av;
      av[0] = (bf16)(e0*a0.x + e1*a1.x + e2*a2.x + e3*a3.x);
      av[1] = (bf16)(e0*a0.y + e1*a1.y + e2*a2.y + e3*a3.y);
      av[2] = (bf16)(e0*a0.z + e1*a1.z + e2*a2.z + e3*a3.z);
      av[3] = (bf16)(e0*a0.w + e1*a1.w + e2*a2.w + e3*a3.w);
      av[4] = (bf16)(e0*b0v.x + e1*b1v.x + e2*b2v.x + e3*b3v.x);
      av[5] = (bf16)(e0*b0v.y + e1*b1v.y + e2*b2v.y + e3*b3v.y);
      av[6] = (bf16)(e0*b0v.z + e1*b1v.z + e2*b2v.z + e3*b3v.z);
      av[7] = (bf16)(e0*b0v.w + e1*b1v.w + e2*b2v.w + e3*b3v.w);
      // attfrag[h*4+mt][lane' = g*16 + rl][j]  (wave-local slice)
      *reinterpret_cast<bf16x8*>(&s_regA[(((h*4) + mt)*64 + g*16 + rl)*8]) = av;
    }
  }
  __syncthreads();   // q region (upper) must be fully read before combfrag overwrites it

  // ---- Wo-GEMM + per-head LN; wave w = head w; writes combfrag (upper 16KB) ----
  {
    f32x4 acc[4][2];
    #pragma unroll
    for (int mt = 0; mt < 4; ++mt) { acc[mt][0] = (f32x4)0.f; acc[mt][1] = (f32x4)0.f; }
    const bf16x8* pO = reinterpret_cast<const bf16x8*>(ws + OFF_O);
    bf16x8 b0 = pO[(w*2 + 0)*64 + lane];
    bf16x8 b1 = pO[(w*2 + 1)*64 + lane];
    #pragma unroll
    for (int mt = 0; mt < 4; ++mt) {
      bf16x8 a = *reinterpret_cast<const bf16x8*>(&s_regA[((w*4 + mt)*64 + lane)*8]);
      acc[mt][0] = MFMA16(a, b0, acc[mt][0]);
      acc[mt][1] = MFMA16(a, b1, acc[mt][1]);
    }
    float bo0 = (float)s_bo[w*32 + lc],  bo1 = (float)s_bo[w*32 + 16 + lc];
    float lg0 = (float)s_lng[w*32 + lc], lg1 = (float)s_lng[w*32 + 16 + lc];
    float lb0 = (float)s_lnb[w*32 + lc], lb1 = (float)s_lnb[w*32 + 16 + lc];
    #pragma unroll
    for (int mt = 0; mt < 4; ++mt)
      #pragma unroll
      for (int r = 0; r < 4; ++r) {
        float v0 = acc[mt][0][r] + bo0;
        float v1 = acc[mt][1][r] + bo1;
        float s = v0 + v1, sq = v0*v0 + v1*v1;
        s += __shfl_xor(s, 1, 64);  sq += __shfl_xor(sq, 1, 64);
        s += __shfl_xor(s, 2, 64);  sq += __shfl_xor(sq, 2, 64);
        s += __shfl_xor(s, 4, 64);  sq += __shfl_xor(sq, 4, 64);
        s += __shfl_xor(s, 8, 64);  sq += __shfl_xor(sq, 8, 64);
        float mean = s * (1.f/32.f);
        float var  = sq * (1.f/32.f) - mean*mean;
        float rstd = rsqrtf(var + 1e-5f);
        float n0 = (v0 - mean)*rstd*lg0 + lb0;
        float n1 = (v1 - mean)*rstd*lg1 + lb1;
        int rl = lr*4 + r;
        int base = 8192 + ((w*4 + mt)*64)*8;
        s_regA[base + (16*(lc >> 3)       + rl)*8 + (lane & 7)] = (bf16)n0;
        s_regA[base + (16*(2 + (lc >> 3)) + rl)*8 + (lane & 7)] = (bf16)n1;
      }
  }
  __syncthreads();

  // ---- GEMM2: out_pre = combined(64x128) * Wf(128x256); wave w -> cols [64w,64w+64) ----
  f32x4 acc2[4][4];
  {
    #pragma unroll
    for (int mt = 0; mt < 4; ++mt)
      #pragma unroll
      for (int nt = 0; nt < 4; ++nt) acc2[mt][nt] = (f32x4)0.f;
    const bf16x8* pF = reinterpret_cast<const bf16x8*>(ws + OFF_F);
    #pragma unroll
    for (int ks = 0; ks < 4; ++ks) {
      bf16x8 a[4], bb[4];
      #pragma unroll
      for (int mt = 0; mt < 4; ++mt)
        a[mt] = *reinterpret_cast<const bf16x8*>(&s_regA[8192 + ((ks*4 + mt)*64 + lane)*8]);
      #pragma unroll
      for (int nt = 0; nt < 4; ++nt)
        bb[nt] = pF[(ks*16 + w*4 + nt)*64 + lane];
      #pragma unroll
      for (int mt = 0; mt < 4; ++mt)
        #pragma unroll
        for (int nt = 0; nt < 4; ++nt)
          acc2[mt][nt] = MFMA16(a[mt], bb[nt], acc2[mt][nt]);
    }
    #pragma unroll
    for (int nt = 0; nt < 4; ++nt) {
      float bfv = (float)s_bf[w*64 + nt*16 + lc];
      #pragma unroll
      for (int mt = 0; mt < 4; ++mt)
        #pragma unroll
        for (int r = 0; r < 4; ++r) acc2[mt][nt][r] += bfv;
    }
  }
  __syncthreads();   // all combfrag reads done before opfrag overwrites region A
  {
    #pragma unroll
    for (int mt = 0; mt < 4; ++mt)
      #pragma unroll
      for (int nt = 0; nt < 4; ++nt) {
        int ks3 = w*2 + (nt >> 1);
        #pragma unroll
        for (int r = 0; r < 4; ++r) {
          int lane2 = 16*((nt & 1)*2 + (lc >> 3)) + (lr*4 + r);
          s_regA[((ks3*4 + mt)*64 + lane2)*8 + (lane & 7)] = (bf16)acc2[mt][nt][r];
        }
      }
  }
  __syncthreads();

  // ---- GEMM3: hidden = relu(out_pre(64x256)*Wg1(256x64) + diff*wg1d + bg1); wave w -> cols [16w,16w+16) ----
  {
    f32x4 acc3[4];
    #pragma unroll
    for (int mt = 0; mt < 4; ++mt) acc3[mt] = (f32x4)0.f;
    const bf16x8* pG1 = reinterpret_cast<const bf16x8*>(ws + OFF_G1);
    #pragma unroll
    for (int ks = 0; ks < 8; ++ks) {
      bf16x8 b = pG1[(ks*4 + w)*64 + lane];
      #pragma unroll
      for (int mt = 0; mt < 4; ++mt) {
        bf16x8 a = *reinterpret_cast<const bf16x8*>(&s_regA[((ks*4 + mt)*64 + lane)*8]);
        acc3[mt] = MFMA16(a, b, acc3[mt]);
      }
    }
    int col3 = w*16 + lc;
    float b1v = s_bg1[col3], wdv = s_wg1d[col3];
    #pragma unroll
    for (int mt = 0; mt < 4; ++mt)
      #pragma unroll
      for (int r = 0; r < 4; ++r) {
        int row = mt*16 + lr*4 + r;
        acc3[mt][r] = fmaxf(acc3[mt][r] + b1v + s_diff[row]*wdv, 0.f);
      }
    __syncthreads();   // all opfrag reads done before hidden frag overwrites regA[0:8KB]
    #pragma unroll
    for (int mt = 0; mt < 4; ++mt)
      #pragma unroll
      for (int r = 0; r < 4; ++r)
        s_regA[(((w >> 1)*4 + mt)*64 + 16*((w & 1)*2 + (lc >> 3)) + (lr*4 + r))*8 + (lane & 7)] = (bf16)acc3[mt][r];
  }
  __syncthreads();

  // ---- GEMM4 (two nt-halves to cap live registers): gate = sigmoid(...); val = out_pre*gate + x ----
  {
    const float* xbase = x + (size_t)row0 * D;
    const bf16x8* pG2 = reinterpret_cast<const bf16x8*>(ws + OFF_G2);
    #pragma unroll
    for (int half = 0; half < 2; ++half) {
      f32x4 acc4[4][2];
      #pragma unroll
      for (int mt = 0; mt < 4; ++mt) { acc4[mt][0] = (f32x4)0.f; acc4[mt][1] = (f32x4)0.f; }
      #pragma unroll
      for (int ks = 0; ks < 2; ++ks) {
        bf16x8 a[4], bb[2];
        #pragma unroll
        for (int mt = 0; mt < 4; ++mt)
          a[mt] = *reinterpret_cast<const bf16x8*>(&s_regA[((ks*4 + mt)*64 + lane)*8]);
        #pragma unroll
        for (int n2 = 0; n2 < 2; ++n2)
          bb[n2] = pG2[(ks*16 + w*4 + half*2 + n2)*64 + lane];
        #pragma unroll
        for (int mt = 0; mt < 4; ++mt)
          #pragma unroll
          for (int n2 = 0; n2 < 2; ++n2)
            acc4[mt][n2] = MFMA16(a[mt], bb[n2], acc4[mt][n2]);
      }
      #pragma unroll
      for (int n2 = 0; n2 < 2; ++n2) {
        int nt = half*2 + n2;
        int c = w*64 + nt*16 + lc;
        float bg2v = (float)s_bg2[c];
        #pragma unroll
        for (int mt = 0; mt < 4; ++mt)
          #pragma unroll
          for (int r = 0; r < 4; ++r) {
            int row = mt*16 + lr*4 + r;
            float z = acc4[mt][n2][r] + bg2v;
            float gate = fast_rcp(1.f + fast_exp(-z));
            acc2[mt][nt][r] = acc2[mt][nt][r]*gate + xbase[row*D + c];
          }
      }
    }
  }
  // LN scratch (bytes 8192..) is disjoint from hidden frag (bytes 0..8191): no barrier needed.

  // ---- final LN partials (per row over this wave's 64 cols) ----
  {
    #pragma unroll
    for (int mt = 0; mt < 4; ++mt)
      #pragma unroll
      for (int r = 0; r < 4; ++r) {
        float s = 0.f, sq = 0.f;
        #pragma unroll
        for (int nt = 0; nt < 4; ++nt) {
          float v = acc2[mt][nt][r];
          s += v; sq = fmaf(v, v, sq);
        }
        s += __shfl_xor(s, 1, 64);  sq += __shfl_xor(sq, 1, 64);
        s += __shfl_xor(s, 2, 64);  sq += __shfl_xor(sq, 2, 64);
        s += __shfl_xor(s, 4, 64);  sq += __shfl_xor(sq, 4, 64);
        s += __shfl_xor(s, 8, 64);  sq += __shfl_xor(sq, 8, 64);
        if (lc == 0) {
          int row = mt*16 + lr*4 + r;
          s_lnsum[row*4 + w] = s;
          s_lnsq[row*4 + w]  = sq;
        }
      }
  }
  __syncthreads();
  if (t < ROWS) {
    float s  = s_lnsum[t*4] + s_lnsum[t*4+1] + s_lnsum[t*4+2] + s_lnsum[t*4+3];
    float sq = s_lnsq[t*4]  + s_lnsq[t*4+1]  + s_lnsq[t*4+2]  + s_lnsq[t*4+3];
    float mean = s * (1.f/256.f);
    float var  = sq * (1.f/256.f) - mean*mean;
    s_rmean[t] = mean;
    s_rrstd[t] = rsqrtf(var + 1e-5f);
  }
  __syncthreads();
  {
    float* obase = out + (size_t)row0 * D;
    #pragma unroll
    for (int mt = 0; mt < 4; ++mt)
      #pragma unroll
      for (int r = 0; r < 4; ++r) {
        int row = mt*16 + lr*4 + r;
        float mean = s_rmean[row], rstd = s_rrstd[row];
        #pragma unroll
        for (int nt = 0; nt < 4; ++nt) {
          int c = w*64 + nt*16 + lc;
          obase[row*D + c] = (acc2[mt][nt][r] - mean)*rstd*(float)s_lnFg[c] + (float)s_lnFb[c];
        }
      }
  }
}

extern "C" void kernel_launch(void* const* d_in, const int* in_sizes, int n_in,
                              void* d_out, int out_size, void* d_ws, size_t ws_size,
                              hipStream_t stream) {
  (void)in_sizes; (void)n_in; (void)ws_size; (void)out_size;
  const float* x   = (const float*)d_in[0];
  const float* mp  = (const float*)d_in[1];
  const float* Wq  = (const float*)d_in[2];
  const float* bq  = (const float*)d_in[3];
  const float* pk  = (const float*)d_in[4];
  const float* pv  = (const float*)d_in[5];
  const float* imp = (const float*)d_in[6];
  const float* fa  = (const float*)d_in[7];
  const float* ft  = (const float*)d_in[8];
  const float* Wo  = (const float*)d_in[9];
  const float* bo  = (const float*)d_in[10];
  const float* lng = (const float*)d_in[11];
  const float* lnb = (const float*)d_in[12];
  const float* Wf  = (const float*)d_in[13];
  const float* bf  = (const float*)d_in[14];
  const float* Wg1 = (const float*)d_in[15];
  const float* bg1 = (const float*)d_in[16];
  const float* Wg2 = (const float*)d_in[17];
  const float* bg2 = (const float*)d_in[18];
  const float* lnFg= (const float*)d_in[19];
  const float* lnFb= (const float*)d_in[20];
  float* out = (float*)d_out;
  bf16* ws = (bf16*)d_ws;

  hipLaunchKernelGGL(prep_kernel, dim3((NPACK + 255)/256), dim3(256), 0, stream,
                     Wq, Wf, Wg1, Wg2, Wo, ws);
  hipLaunchKernelGGL(faiia_kernel, dim3(NROWS_TOT / ROWS), dim3(256), 0, stream,
                     x, mp, bq, pk, pv, imp, fa, ft, bo, lng, lnb,
                     bf, Wg1, bg1, bg2, lnFg, lnFb, ws, out);
}